// Round 2
// baseline (218.375 us; speedup 1.0000x reference)
//
#include <hip/hip_runtime.h>

// ALiBi bias materialization:
//   out[h, i, j] = (j > i) ? -slopes[h] * (j - i) : 0.0f
// H=16, S=4096, float32 output [16, 4096, 4096] = 1.074 GB. Pure write-BW-bound.
//
// Structure: grid.y = h (16 planes) so the slope is a hoisted wave-uniform
// scalar. Each thread issues 16 fully-unrolled, independent nontemporal
// dwordx4 stores (wave writes 1 KiB/instruction, contiguous).

#define ALIBI_S 4096
#define ALIBI_H 16
#define UNROLL  16
#define BLOCK   256

typedef float f32x4 __attribute__((ext_vector_type(4)));

__global__ __launch_bounds__(BLOCK) void alibi_bias_kernel(
    const float* __restrict__ slopes,
    f32x4* __restrict__ out)
{
    const int h = blockIdx.y;
    const float ns = -slopes[h];  // wave-uniform scalar load, once per thread

    // float4 index within this h-plane (plane = S*S/4 = 2^22 float4s)
    const unsigned int base_f4 = blockIdx.x * (BLOCK * UNROLL) + threadIdx.x;
    f32x4* plane = out + ((size_t)h << 22);

#pragma unroll
    for (int k = 0; k < UNROLL; ++k) {
        const unsigned int f = base_f4 + (unsigned int)k * BLOCK;  // stride 4 KB
        const unsigned int e = f << 2;            // element index within plane
        const int i = (int)(e >> 12);             // row (S = 2^12)
        const int j = (int)(e & 4095u);           // first of 4 consecutive cols

        f32x4 v;
        v.x = (j + 0 > i) ? ns * (float)(j + 0 - i) : 0.0f;
        v.y = (j + 1 > i) ? ns * (float)(j + 1 - i) : 0.0f;
        v.z = (j + 2 > i) ? ns * (float)(j + 2 - i) : 0.0f;
        v.w = (j + 3 > i) ? ns * (float)(j + 3 - i) : 0.0f;

        __builtin_nontemporal_store(v, plane + f);
    }
}

extern "C" void kernel_launch(void* const* d_in, const int* in_sizes, int n_in,
                              void* d_out, int out_size, void* d_ws, size_t ws_size,
                              hipStream_t stream) {
    const float* slopes = (const float*)d_in[0];
    // d_in[1] is seq_len (=4096), compile-time constant here.
    f32x4* out = (f32x4*)d_out;

    // Per plane: S*S/4 = 4,194,304 float4s; per block: 256*16 = 4096 float4s
    // -> 1024 blocks per plane, 16 planes.
    dim3 grid(ALIBI_S * ALIBI_S / 4 / (BLOCK * UNROLL), ALIBI_H);
    alibi_bias_kernel<<<grid, BLOCK, 0, stream>>>(slopes, out);
}

// Round 3
// 202.928 us; speedup vs baseline: 1.0761x; 1.0761x over previous
//
#include <hip/hip_runtime.h>

// ALiBi bias materialization:
//   out[h, i, j] = (j > i) ? -slopes[h] * (j - i) : 0.0f
// H=16, S=4096, float32 output [16, 4096, 4096] = 1.074 GB. Pure write-BW-bound.
//
// R3 = R2 minus nontemporal stores (clean A/B: nt suspected as the R2
// regression — normal write-back L2 coalesces full lines before HBM).
// grid.y = h (hoisted wave-uniform slope), 16 fully-unrolled dwordx4
// stores/thread, exact-cover grid.

#define ALIBI_S 4096
#define ALIBI_H 16
#define UNROLL  16
#define BLOCK   256

typedef float f32x4 __attribute__((ext_vector_type(4)));

__global__ __launch_bounds__(BLOCK) void alibi_bias_kernel(
    const float* __restrict__ slopes,
    f32x4* __restrict__ out)
{
    const int h = blockIdx.y;
    const float ns = -slopes[h];  // wave-uniform scalar load, once per thread

    // float4 index within this h-plane (plane = S*S/4 = 2^22 float4s)
    const unsigned int base_f4 = blockIdx.x * (BLOCK * UNROLL) + threadIdx.x;
    f32x4* plane = out + ((size_t)h << 22);

#pragma unroll
    for (int k = 0; k < UNROLL; ++k) {
        const unsigned int f = base_f4 + (unsigned int)k * BLOCK;  // stride 4 KB
        const unsigned int e = f << 2;            // element index within plane
        const int i = (int)(e >> 12);             // row (S = 2^12)
        const int j = (int)(e & 4095u);           // first of 4 consecutive cols

        f32x4 v;
        v.x = (j + 0 > i) ? ns * (float)(j + 0 - i) : 0.0f;
        v.y = (j + 1 > i) ? ns * (float)(j + 1 - i) : 0.0f;
        v.z = (j + 2 > i) ? ns * (float)(j + 2 - i) : 0.0f;
        v.w = (j + 3 > i) ? ns * (float)(j + 3 - i) : 0.0f;

        plane[f] = v;  // normal write-back store (no nt)
    }
}

extern "C" void kernel_launch(void* const* d_in, const int* in_sizes, int n_in,
                              void* d_out, int out_size, void* d_ws, size_t ws_size,
                              hipStream_t stream) {
    const float* slopes = (const float*)d_in[0];
    // d_in[1] is seq_len (=4096), compile-time constant here.
    f32x4* out = (f32x4*)d_out;

    // Per plane: S*S/4 = 4,194,304 float4s; per block: 256*16 = 4096 float4s
    // -> 1024 blocks per plane, 16 planes.
    dim3 grid(ALIBI_S * ALIBI_S / 4 / (BLOCK * UNROLL), ALIBI_H);
    alibi_bias_kernel<<<grid, BLOCK, 0, stream>>>(slopes, out);
}